// Round 12
// baseline (213.438 us; speedup 1.0000x reference)
//
#include <hip/hip_runtime.h>
#include <hip/hip_fp16.h>
#include <cstddef>

#define N_ 1024
#define M_ 1024
#define D_ 1024
#define G_ 16
#define DG_ 64

typedef __bf16 bf16x8 __attribute__((ext_vector_type(8)));
typedef _Float16 f16x8 __attribute__((ext_vector_type(8)));
typedef float f32x4 __attribute__((ext_vector_type(4)));

// Fragment-major layout helpers (R4/R9/R11, verified passing).
__device__ __forceinline__ size_t qkf_idx(int g, int rb, int ks, int lane) {
    return ((((size_t)(g * 64 + rb)) * 2 + ks) * 64 + lane) * 8;
}
__device__ __forceinline__ size_t vf_idx(int g, int ot, int mc, int lane) {
    return ((((size_t)(g * 4 + ot)) * 32 + mc) * 64 + lane) * 8;
}
__device__ __forceinline__ size_t awt_idx(int g, int mb, int n, int quad) {
    return (((size_t)(g * 64 + mb)) * 1024 + n) * 16 + quad * 4;
}

// ---------------------------------------------------------------------------
// Fused dispatch #1: blocks 0..191 = gemm (128x128 tile, BK=128 -> 8 K-iters,
// fp32 weights transpose-cast during LDS staging); blocks 192..4287 = posbias.
// BK=128 halves the per-block barrier+vmcnt(0)-drain count (the measured cost
// of the latency-bound gemm path; occupancy is grid-limited so bigger LDS is
// free for the gemm blocks).
// ---------------------------------------------------------------------------
__global__ __launch_bounds__(256)
void fused_mid(const float* __restrict__ roi, const float* __restrict__ ref,
               const float* __restrict__ Wq, const float* __restrict__ Wk,
               const float* __restrict__ Wv,
               const float* __restrict__ bq, const float* __restrict__ bk,
               __bf16* __restrict__ Qf, __bf16* __restrict__ Kf,
               __bf16* __restrict__ Vf,
               const float* __restrict__ rois1, const float* __restrict__ rois2,
               const float* __restrict__ Wg, const float* __restrict__ bg,
               __half* __restrict__ AWt)
{
    __shared__ __align__(16) char smem[69632];   // As 128x136 + Bs 128x136 (bf16)
    const int b = blockIdx.x;
    const int tid = threadIdx.x;
    const int w = tid >> 6, lane = tid & 63;
    const int quad = lane >> 4, l15 = lane & 15;

    if (b < 192) {
        // ---------------- GEMM branch ----------------
        const int z = b >> 6, t6 = b & 63;
        const float* A = (z == 0) ? roi : ref;
        const float* Wf = (z == 0) ? Wq : (z == 1) ? Wk : Wv;
        const int i0 = (t6 >> 3) * 128, j0 = (t6 & 7) * 128;
        const int iw = (w & 1) * 64, jw = (w >> 1) * 64;

        __bf16(*As)[136] = (__bf16(*)[136])smem;
        __bf16(*Bs)[136] = (__bf16(*)[136])(smem + 34816);

        f32x4 acc[4][4] = {};

        for (int k0 = 0; k0 < D_; k0 += 128) {
            __syncthreads();
            // A: 128 rows x 32 float4 chunks (cast fp32->bf16)
            #pragma unroll
            for (int it = 0; it < 16; ++it) {
                const int idx = tid + 256 * it;
                const int row = idx >> 5, c = idx & 31;
                float4 a = *(const float4*)&A[(size_t)(i0 + row) * D_ + k0 + c * 4];
                __bf16 p[4] = {(__bf16)a.x, (__bf16)a.y, (__bf16)a.z, (__bf16)a.w};
                *(uint2*)&As[row][c * 4] = *(const uint2*)p;
            }
            if (z < 2) {
                // B = W^T: transpose-cast during staging.
                // Bs[j][k] = (bf16) W[k0+k][j0+j]; coalesced dword loads down k.
                #pragma unroll
                for (int it = 0; it < 16; ++it) {
                    const int idx = tid + 256 * it;
                    const int jl = idx & 127;          // j-local (fast: coalesced)
                    const int kc = idx >> 7;           // 0..31 -> k-local 4*kc
                    const float* src = &Wf[(size_t)(k0 + kc * 4) * D_ + j0 + jl];
                    __bf16 p[4];
                    p[0] = (__bf16)src[0];
                    p[1] = (__bf16)src[D_];
                    p[2] = (__bf16)src[2 * D_];
                    p[3] = (__bf16)src[3 * D_];
                    *(uint2*)&Bs[jl][kc * 4] = *(const uint2*)p;
                }
            } else {
                // Wv already [go][d]: stage with cast, like A.
                #pragma unroll
                for (int it = 0; it < 16; ++it) {
                    const int idx = tid + 256 * it;
                    const int row = idx >> 5, c = idx & 31;
                    float4 a = *(const float4*)&Wf[(size_t)(j0 + row) * D_ + k0 + c * 4];
                    __bf16 p[4] = {(__bf16)a.x, (__bf16)a.y, (__bf16)a.z, (__bf16)a.w};
                    *(uint2*)&Bs[row][c * 4] = *(const uint2*)p;
                }
            }
            __syncthreads();
            #pragma unroll
            for (int ks = 0; ks < 4; ++ks) {
                bf16x8 af[4], bfr[4];
                #pragma unroll
                for (int t = 0; t < 4; ++t) {
                    af[t]  = *(const bf16x8*)&As[iw + t * 16 + l15][ks * 32 + quad * 8];
                    bfr[t] = *(const bf16x8*)&Bs[jw + t * 16 + l15][ks * 32 + quad * 8];
                }
                #pragma unroll
                for (int ti = 0; ti < 4; ++ti)
                    #pragma unroll
                    for (int tj = 0; tj < 4; ++tj)
                        acc[ti][tj] = __builtin_amdgcn_mfma_f32_16x16x32_bf16(
                            af[ti], bfr[tj], acc[ti][tj], 0, 0, 0);
            }
        }

        if (z < 2) {
            const float* bias = (z == 0) ? bq : bk;
            __bf16* dst = (z == 0) ? Qf : Kf;
            const float scale = (z == 0) ? 0.125f : 1.0f;
            #pragma unroll
            for (int ti = 0; ti < 4; ++ti) {
                const int rb = (i0 + iw + ti * 16) >> 4;
                #pragma unroll
                for (int tj = 0; tj < 4; ++tj) {
                    const int go = j0 + jw + tj * 16 + l15;
                    const int g = go >> 6, ks = (go >> 5) & 1;
                    const int lanef = ((go >> 3) & 3) * 16;
                    const int jf = go & 7;
                    const float bb = bias[go];
                    __bf16* base = dst + qkf_idx(g, rb, ks, 0) + jf;
                    #pragma unroll
                    for (int r = 0; r < 4; ++r)
                        base[(size_t)(lanef + quad * 4 + r) * 8] =
                            (__bf16)((acc[ti][tj][r] + bb) * scale);
                }
            }
        } else {
            #pragma unroll
            for (int ti = 0; ti < 4; ++ti) {
                const int mbase = i0 + iw + ti * 16 + quad * 4;
                const int mc = mbase >> 5, quadv = (mbase >> 3) & 3, jb = mbase & 7;
                #pragma unroll
                for (int tj = 0; tj < 4; ++tj) {
                    const int go = j0 + jw + tj * 16 + l15;
                    const int g = go >> 6, ot = (go >> 4) & 3, o15 = go & 15;
                    __bf16 p[4];
                    #pragma unroll
                    for (int r = 0; r < 4; ++r) p[r] = (__bf16)acc[ti][tj][r];
                    *(uint2*)&Vf[vf_idx(g, ot, mc, quadv * 16 + o15) + jb] =
                        *(const uint2*)p;
                }
            }
        }
        return;
    }

    // ---------------- posbias branch (R9/R11 verbatim) ----------------
    const int pb = b - 192;
    const int n = pb >> 2;
    const int m0w = (pb & 3) * 256 + w * 64;

    const float xmin = rois1[n * 4 + 0], ymin = rois1[n * 4 + 1];
    const float xmax = rois1[n * 4 + 2], ymax = rois1[n * 4 + 3];
    const float wn  = xmax - xmin + 1.f, hn  = ymax - ymin + 1.f;
    const float cxn = 0.5f * (xmin + xmax), cyn = 0.5f * (ymin + ymax);

    f16x8 wgf[2];
    #pragma unroll
    for (int ks = 0; ks < 2; ++ks) {
        const float* p = &Wg[l15 * 64 + ks * 32 + quad * 8];
        float4 a = *(const float4*)p;
        float4 bb = *(const float4*)(p + 4);
        wgf[ks][0] = (_Float16)a.x; wgf[ks][1] = (_Float16)a.y;
        wgf[ks][2] = (_Float16)a.z; wgf[ks][3] = (_Float16)a.w;
        wgf[ks][4] = (_Float16)bb.x; wgf[ks][5] = (_Float16)bb.y;
        wgf[ks][6] = (_Float16)bb.z; wgf[ks][7] = (_Float16)bb.w;
    }
    const float bgv = bg[l15];

    const float fr8[8] = {100.0f, 42.16965f, 17.782794f, 7.4989421f,
                          3.1622777f, 1.3335214f, 0.56234133f, 0.23713737f};
    const float phase = (quad & 1) ? 1.5707963267948966f : 0.f;

    #pragma unroll
    for (int ti = 0; ti < 4; ++ti) {
        const int mt0 = m0w + ti * 16;
        const int m = mt0 + l15;
        float4 r2 = *(const float4*)&rois2[m * 4];
        const float wr  = r2.z - r2.x + 1.f, hr  = r2.w - r2.y + 1.f;
        const float cxr = 0.5f * (r2.x + r2.z), cyr = 0.5f * (r2.y + r2.w);

        const float f0 = __logf(fabsf((cxn - cxr) / wn) + 0.001f);
        const float f1 = __logf(fabsf((cyn - cyr) / hn) + 0.001f);
        const float f2 = __logf(wn / wr);
        const float f3 = __logf(hn / hr);
        const float fa = (quad & 2) ? f1 : f0;
        const float fb = (quad & 2) ? f3 : f2;

        f32x4 acc = {};
        #pragma unroll
        for (int ks = 0; ks < 2; ++ks) {
            const float feat = ks ? fb : fa;
            f16x8 ef;
            #pragma unroll
            for (int j = 0; j < 8; ++j)
                ef[j] = (_Float16)__sinf(fmaf(feat, fr8[j], phase));
            acc = __builtin_amdgcn_mfma_f32_16x16x32_f16(ef, wgf[ks], acc, 0, 0, 0);
        }

        __half p[4];
        #pragma unroll
        for (int r = 0; r < 4; ++r)
            p[r] = __float2half(fmaxf(acc[r] + bgv, 0.f) + 1e-6f);
        *(uint2*)&AWt[awt_idx(l15, mt0 >> 4, n, quad)] = *(const uint2*)p;
    }
}

// ---------------------------------------------------------------------------
// Wave-autonomous MFMA attention (R4/R9/R11 verbatim). Block = (16-n band, g);
// 4 waves each own a 256-m chunk (no barriers in m-loop); LDS combine.
// ---------------------------------------------------------------------------
__global__ __launch_bounds__(256)
void attn_mfma(const __bf16* __restrict__ Qf, const __bf16* __restrict__ Kf,
               const __bf16* __restrict__ Vf, const __half* __restrict__ AWt,
               const float* __restrict__ bv, float* __restrict__ out)
{
    __shared__ __bf16 Ps[4][2][16][72];
    __shared__ float accb[4][64][17];
    __shared__ float lsb[4][16];

    const int tid = threadIdx.x;
    const int w = tid >> 6, lane = tid & 63;
    const int quad = lane >> 4, l15 = lane & 15;
    const int nb = blockIdx.x, n0 = nb * 16, g = blockIdx.y;

    bf16x8 qf[2];
    qf[0] = *(const bf16x8*)&Qf[qkf_idx(g, nb, 0, lane)];
    qf[1] = *(const bf16x8*)&Qf[qkf_idx(g, nb, 1, lane)];

    f32x4 acc[4] = {};
    float llocal = 0.f;

    #pragma unroll
    for (int t64 = 0; t64 < 4; ++t64) {
        const int mt = w * 4 + t64;
        const int buf = t64 & 1;

        f32x4 s[4];
        #pragma unroll
        for (int t = 0; t < 4; ++t) {
            bf16x8 ka0 = *(const bf16x8*)&Kf[qkf_idx(g, mt * 4 + t, 0, lane)];
            bf16x8 ka1 = *(const bf16x8*)&Kf[qkf_idx(g, mt * 4 + t, 1, lane)];
            f32x4 z = {};
            z = __builtin_amdgcn_mfma_f32_16x16x32_bf16(ka0, qf[0], z, 0, 0, 0);
            s[t] = __builtin_amdgcn_mfma_f32_16x16x32_bf16(ka1, qf[1], z, 0, 0, 0);
        }

        #pragma unroll
        for (int t = 0; t < 4; ++t) {
            uint2 au = *(const uint2*)&AWt[awt_idx(g, mt * 4 + t, n0 + l15, quad)];
            const __half* a4 = (const __half*)&au;
            __bf16 pk[4];
            #pragma unroll
            for (int r = 0; r < 4; ++r) {
                const float p = __half2float(a4[r]) * __expf(s[t][r]);
                llocal += p;
                pk[r] = (__bf16)p;
            }
            *(uint2*)&Ps[w][buf][l15][t * 16 + quad * 4] = *(const uint2*)pk;
        }

        #pragma unroll
        for (int mcl = 0; mcl < 2; ++mcl) {
            bf16x8 pbf = *(const bf16x8*)&Ps[w][buf][l15][mcl * 32 + quad * 8];
            #pragma unroll
            for (int ot = 0; ot < 4; ++ot) {
                bf16x8 va = *(const bf16x8*)&Vf[vf_idx(g, ot, mt * 2 + mcl, lane)];
                acc[ot] = __builtin_amdgcn_mfma_f32_16x16x32_bf16(va, pbf, acc[ot], 0, 0, 0);
            }
        }
    }

    llocal += __shfl_xor(llocal, 16, 64);
    llocal += __shfl_xor(llocal, 32, 64);

    #pragma unroll
    for (int ot = 0; ot < 4; ++ot)
        #pragma unroll
        for (int r = 0; r < 4; ++r)
            accb[w][ot * 16 + quad * 4 + r][l15] = acc[ot][r];
    if (quad == 0) lsb[w][l15] = llocal;
    __syncthreads();

    const float lt = lsb[0][l15] + lsb[1][l15] + lsb[2][l15] + lsb[3][l15];
    const float inv = 1.f / lt;
    #pragma unroll
    for (int r = 0; r < 4; ++r) {
        const int o = w * 16 + quad * 4 + r;
        const int ogl = g * 64 + o;
        const float v = accb[0][o][l15] + accb[1][o][l15] +
                        accb[2][o][l15] + accb[3][o][l15];
        out[(size_t)(n0 + l15) * D_ + ogl] = v * inv + bv[ogl];
    }
}

extern "C" void kernel_launch(void* const* d_in, const int* in_sizes, int n_in,
                              void* d_out, int out_size, void* d_ws, size_t ws_size,
                              hipStream_t stream) {
    const float* roi_feat = (const float*)d_in[0];
    const float* ref_feat = (const float*)d_in[1];
    const float* rois1    = (const float*)d_in[2];
    const float* rois2    = (const float*)d_in[3];
    const float* Wq       = (const float*)d_in[4];
    const float* bq       = (const float*)d_in[5];
    const float* Wk       = (const float*)d_in[6];
    const float* bk       = (const float*)d_in[7];
    const float* Wg       = (const float*)d_in[8];
    const float* bg       = (const float*)d_in[9];
    const float* Wv       = (const float*)d_in[10];
    const float* bv       = (const float*)d_in[11];
    float* out = (float*)d_out;

    // ws (bytes): Qf 0-2M | Kf 2-4M | Vf 4-6M | AWt 6-38M
    char* ws = (char*)d_ws;
    __bf16* Qf  = (__bf16*)(ws + 0);
    __bf16* Kf  = (__bf16*)(ws + (2u << 20));
    __bf16* Vf  = (__bf16*)(ws + (4u << 20));
    __half* AWt = (__half*)(ws + (6u << 20));

    dim3 blk(256);
    fused_mid<<<dim3(4288), blk, 0, stream>>>(roi_feat, ref_feat, Wq, Wk, Wv,
                                              bq, bk, Qf, Kf, Vf,
                                              rois1, rois2, Wg, bg, AWt);
    attn_mfma<<<dim3(64, 16), blk, 0, stream>>>(Qf, Kf, Vf, AWt, bv, out);
}

// Round 13
// 148.838 us; speedup vs baseline: 1.4340x; 1.4340x over previous
//
#include <hip/hip_runtime.h>
#include <hip/hip_fp16.h>
#include <cstddef>

#define N_ 1024
#define M_ 1024
#define D_ 1024
#define G_ 16
#define DG_ 64

typedef __bf16 bf16x8 __attribute__((ext_vector_type(8)));
typedef _Float16 f16x8 __attribute__((ext_vector_type(8)));
typedef float f32x4 __attribute__((ext_vector_type(4)));

// Fragment-major layout helpers.
__device__ __forceinline__ size_t qkf_idx(int g, int rb, int ks, int lane) {
    return ((((size_t)(g * 64 + rb)) * 2 + ks) * 64 + lane) * 8;
}
__device__ __forceinline__ size_t vf_idx(int g, int ot, int mc, int lane) {
    return ((((size_t)(g * 4 + ot)) * 32 + mc) * 64 + lane) * 8;
}
// AWt layout v2: [mb(64)][n(1024)][g(16)][m16(16)].
// posbias (g=l15, quad vary per lane; n,mb uniform) -> one coalesced 512B
// window per (n,mb). attn reads 16x32B within 8KB (hidden by MFMA chains).
__device__ __forceinline__ size_t awt_idx(int g, int mb, int n, int quad) {
    return (((size_t)(mb * 1024 + n)) * 16 + g) * 16 + quad * 4;
}

// ---------------------------------------------------------------------------
// Fused dispatch #1 (R11 structure, BK=64): blocks 0..191 = gemm (128x128
// tile, fp32 weights transpose-cast during staging); blocks 192..4287 =
// posbias (MFMA f16, coalesced AWt stores).
// ---------------------------------------------------------------------------
__global__ __launch_bounds__(256)
void fused_mid(const float* __restrict__ roi, const float* __restrict__ ref,
               const float* __restrict__ Wq, const float* __restrict__ Wk,
               const float* __restrict__ Wv,
               const float* __restrict__ bq, const float* __restrict__ bk,
               __bf16* __restrict__ Qf, __bf16* __restrict__ Kf,
               __bf16* __restrict__ Vf,
               const float* __restrict__ rois1, const float* __restrict__ rois2,
               const float* __restrict__ Wg, const float* __restrict__ bg,
               __half* __restrict__ AWt)
{
    __shared__ __align__(16) char smem[36864];
    const int b = blockIdx.x;
    const int tid = threadIdx.x;
    const int w = tid >> 6, lane = tid & 63;
    const int quad = lane >> 4, l15 = lane & 15;

    if (b < 192) {
        // ---------------- GEMM branch (R11 verbatim) ----------------
        const int z = b >> 6, t6 = b & 63;
        const float* A = (z == 0) ? roi : ref;
        const float* Wf = (z == 0) ? Wq : (z == 1) ? Wk : Wv;
        const int i0 = (t6 >> 3) * 128, j0 = (t6 & 7) * 128;
        const int iw = (w & 1) * 64, jw = (w >> 1) * 64;

        __bf16(*As)[72] = (__bf16(*)[72])smem;
        __bf16(*Bs)[72] = (__bf16(*)[72])(smem + 18432);

        f32x4 acc[4][4] = {};

        for (int k0 = 0; k0 < D_; k0 += 64) {
            __syncthreads();
            #pragma unroll
            for (int it = 0; it < 8; ++it) {
                const int idx = tid + 256 * it;
                const int row = idx >> 4, c = idx & 15;
                float4 a = *(const float4*)&A[(size_t)(i0 + row) * D_ + k0 + c * 4];
                __bf16 p[4] = {(__bf16)a.x, (__bf16)a.y, (__bf16)a.z, (__bf16)a.w};
                *(uint2*)&As[row][c * 4] = *(const uint2*)p;
            }
            if (z < 2) {
                #pragma unroll
                for (int it = 0; it < 8; ++it) {
                    const int idx = tid + 256 * it;
                    const int jl = idx & 127;
                    const int kc = idx >> 7;
                    const float* src = &Wf[(size_t)(k0 + kc * 4) * D_ + j0 + jl];
                    __bf16 p[4];
                    p[0] = (__bf16)src[0];
                    p[1] = (__bf16)src[D_];
                    p[2] = (__bf16)src[2 * D_];
                    p[3] = (__bf16)src[3 * D_];
                    *(uint2*)&Bs[jl][kc * 4] = *(const uint2*)p;
                }
            } else {
                #pragma unroll
                for (int it = 0; it < 8; ++it) {
                    const int idx = tid + 256 * it;
                    const int row = idx >> 4, c = idx & 15;
                    float4 a = *(const float4*)&Wf[(size_t)(j0 + row) * D_ + k0 + c * 4];
                    __bf16 p[4] = {(__bf16)a.x, (__bf16)a.y, (__bf16)a.z, (__bf16)a.w};
                    *(uint2*)&Bs[row][c * 4] = *(const uint2*)p;
                }
            }
            __syncthreads();
            #pragma unroll
            for (int ks = 0; ks < 2; ++ks) {
                bf16x8 af[4], bfr[4];
                #pragma unroll
                for (int t = 0; t < 4; ++t) {
                    af[t]  = *(const bf16x8*)&As[iw + t * 16 + l15][ks * 32 + quad * 8];
                    bfr[t] = *(const bf16x8*)&Bs[jw + t * 16 + l15][ks * 32 + quad * 8];
                }
                #pragma unroll
                for (int ti = 0; ti < 4; ++ti)
                    #pragma unroll
                    for (int tj = 0; tj < 4; ++tj)
                        acc[ti][tj] = __builtin_amdgcn_mfma_f32_16x16x32_bf16(
                            af[ti], bfr[tj], acc[ti][tj], 0, 0, 0);
            }
        }

        if (z < 2) {
            const float* bias = (z == 0) ? bq : bk;
            __bf16* dst = (z == 0) ? Qf : Kf;
            const float scale = (z == 0) ? 0.125f : 1.0f;
            #pragma unroll
            for (int ti = 0; ti < 4; ++ti) {
                const int rb = (i0 + iw + ti * 16) >> 4;
                #pragma unroll
                for (int tj = 0; tj < 4; ++tj) {
                    const int go = j0 + jw + tj * 16 + l15;
                    const int g = go >> 6, ks = (go >> 5) & 1;
                    const int lanef = ((go >> 3) & 3) * 16;
                    const int jf = go & 7;
                    const float bb = bias[go];
                    __bf16* base = dst + qkf_idx(g, rb, ks, 0) + jf;
                    #pragma unroll
                    for (int r = 0; r < 4; ++r)
                        base[(size_t)(lanef + quad * 4 + r) * 8] =
                            (__bf16)((acc[ti][tj][r] + bb) * scale);
                }
            }
        } else {
            #pragma unroll
            for (int ti = 0; ti < 4; ++ti) {
                const int mbase = i0 + iw + ti * 16 + quad * 4;
                const int mc = mbase >> 5, quadv = (mbase >> 3) & 3, jb = mbase & 7;
                #pragma unroll
                for (int tj = 0; tj < 4; ++tj) {
                    const int go = j0 + jw + tj * 16 + l15;
                    const int g = go >> 6, ot = (go >> 4) & 3, o15 = go & 15;
                    __bf16 p[4];
                    #pragma unroll
                    for (int r = 0; r < 4; ++r) p[r] = (__bf16)acc[ti][tj][r];
                    *(uint2*)&Vf[vf_idx(g, ot, mc, quadv * 16 + o15) + jb] =
                        *(const uint2*)p;
                }
            }
        }
        return;
    }

    // ---------------- posbias branch (R11 verbatim; new awt layout) ----------
    const int pb = b - 192;
    const int n = pb >> 2;
    const int m0w = (pb & 3) * 256 + w * 64;

    const float xmin = rois1[n * 4 + 0], ymin = rois1[n * 4 + 1];
    const float xmax = rois1[n * 4 + 2], ymax = rois1[n * 4 + 3];
    const float wn  = xmax - xmin + 1.f, hn  = ymax - ymin + 1.f;
    const float cxn = 0.5f * (xmin + xmax), cyn = 0.5f * (ymin + ymax);

    f16x8 wgf[2];
    #pragma unroll
    for (int ks = 0; ks < 2; ++ks) {
        const float* p = &Wg[l15 * 64 + ks * 32 + quad * 8];
        float4 a = *(const float4*)p;
        float4 bb = *(const float4*)(p + 4);
        wgf[ks][0] = (_Float16)a.x; wgf[ks][1] = (_Float16)a.y;
        wgf[ks][2] = (_Float16)a.z; wgf[ks][3] = (_Float16)a.w;
        wgf[ks][4] = (_Float16)bb.x; wgf[ks][5] = (_Float16)bb.y;
        wgf[ks][6] = (_Float16)bb.z; wgf[ks][7] = (_Float16)bb.w;
    }
    const float bgv = bg[l15];

    const float fr8[8] = {100.0f, 42.16965f, 17.782794f, 7.4989421f,
                          3.1622777f, 1.3335214f, 0.56234133f, 0.23713737f};
    const float phase = (quad & 1) ? 1.5707963267948966f : 0.f;

    #pragma unroll
    for (int ti = 0; ti < 4; ++ti) {
        const int mt0 = m0w + ti * 16;
        const int m = mt0 + l15;
        float4 r2 = *(const float4*)&rois2[m * 4];
        const float wr  = r2.z - r2.x + 1.f, hr  = r2.w - r2.y + 1.f;
        const float cxr = 0.5f * (r2.x + r2.z), cyr = 0.5f * (r2.y + r2.w);

        const float f0 = __logf(fabsf((cxn - cxr) / wn) + 0.001f);
        const float f1 = __logf(fabsf((cyn - cyr) / hn) + 0.001f);
        const float f2 = __logf(wn / wr);
        const float f3 = __logf(hn / hr);
        const float fa = (quad & 2) ? f1 : f0;
        const float fb = (quad & 2) ? f3 : f2;

        f32x4 acc = {};
        #pragma unroll
        for (int ks = 0; ks < 2; ++ks) {
            const float feat = ks ? fb : fa;
            f16x8 ef;
            #pragma unroll
            for (int j = 0; j < 8; ++j)
                ef[j] = (_Float16)__sinf(fmaf(feat, fr8[j], phase));
            acc = __builtin_amdgcn_mfma_f32_16x16x32_f16(ef, wgf[ks], acc, 0, 0, 0);
        }

        __half p[4];
        #pragma unroll
        for (int r = 0; r < 4; ++r)
            p[r] = __float2half(fmaxf(acc[r] + bgv, 0.f) + 1e-6f);
        *(uint2*)&AWt[awt_idx(l15, mt0 >> 4, n, quad)] = *(const uint2*)p;
    }
}

// ---------------------------------------------------------------------------
// Wave-autonomous MFMA attention (R11 verbatim; awt_idx body changed only).
// ---------------------------------------------------------------------------
__global__ __launch_bounds__(256)
void attn_mfma(const __bf16* __restrict__ Qf, const __bf16* __restrict__ Kf,
               const __bf16* __restrict__ Vf, const __half* __restrict__ AWt,
               const float* __restrict__ bv, float* __restrict__ out)
{
    __shared__ __bf16 Ps[4][2][16][72];
    __shared__ float accb[4][64][17];
    __shared__ float lsb[4][16];

    const int tid = threadIdx.x;
    const int w = tid >> 6, lane = tid & 63;
    const int quad = lane >> 4, l15 = lane & 15;
    const int nb = blockIdx.x, n0 = nb * 16, g = blockIdx.y;

    bf16x8 qf[2];
    qf[0] = *(const bf16x8*)&Qf[qkf_idx(g, nb, 0, lane)];
    qf[1] = *(const bf16x8*)&Qf[qkf_idx(g, nb, 1, lane)];

    f32x4 acc[4] = {};
    float llocal = 0.f;

    #pragma unroll
    for (int t64 = 0; t64 < 4; ++t64) {
        const int mt = w * 4 + t64;
        const int buf = t64 & 1;

        f32x4 s[4];
        #pragma unroll
        for (int t = 0; t < 4; ++t) {
            bf16x8 ka0 = *(const bf16x8*)&Kf[qkf_idx(g, mt * 4 + t, 0, lane)];
            bf16x8 ka1 = *(const bf16x8*)&Kf[qkf_idx(g, mt * 4 + t, 1, lane)];
            f32x4 z = {};
            z = __builtin_amdgcn_mfma_f32_16x16x32_bf16(ka0, qf[0], z, 0, 0, 0);
            s[t] = __builtin_amdgcn_mfma_f32_16x16x32_bf16(ka1, qf[1], z, 0, 0, 0);
        }

        #pragma unroll
        for (int t = 0; t < 4; ++t) {
            uint2 au = *(const uint2*)&AWt[awt_idx(g, mt * 4 + t, n0 + l15, quad)];
            const __half* a4 = (const __half*)&au;
            __bf16 pk[4];
            #pragma unroll
            for (int r = 0; r < 4; ++r) {
                const float p = __half2float(a4[r]) * __expf(s[t][r]);
                llocal += p;
                pk[r] = (__bf16)p;
            }
            *(uint2*)&Ps[w][buf][l15][t * 16 + quad * 4] = *(const uint2*)pk;
        }

        #pragma unroll
        for (int mcl = 0; mcl < 2; ++mcl) {
            bf16x8 pbf = *(const bf16x8*)&Ps[w][buf][l15][mcl * 32 + quad * 8];
            #pragma unroll
            for (int ot = 0; ot < 4; ++ot) {
                bf16x8 va = *(const bf16x8*)&Vf[vf_idx(g, ot, mt * 2 + mcl, lane)];
                acc[ot] = __builtin_amdgcn_mfma_f32_16x16x32_bf16(va, pbf, acc[ot], 0, 0, 0);
            }
        }
    }

    llocal += __shfl_xor(llocal, 16, 64);
    llocal += __shfl_xor(llocal, 32, 64);

    #pragma unroll
    for (int ot = 0; ot < 4; ++ot)
        #pragma unroll
        for (int r = 0; r < 4; ++r)
            accb[w][ot * 16 + quad * 4 + r][l15] = acc[ot][r];
    if (quad == 0) lsb[w][l15] = llocal;
    __syncthreads();

    const float lt = lsb[0][l15] + lsb[1][l15] + lsb[2][l15] + lsb[3][l15];
    const float inv = 1.f / lt;
    #pragma unroll
    for (int r = 0; r < 4; ++r) {
        const int o = w * 16 + quad * 4 + r;
        const int ogl = g * 64 + o;
        const float v = accb[0][o][l15] + accb[1][o][l15] +
                        accb[2][o][l15] + accb[3][o][l15];
        out[(size_t)(n0 + l15) * D_ + ogl] = v * inv + bv[ogl];
    }
}

extern "C" void kernel_launch(void* const* d_in, const int* in_sizes, int n_in,
                              void* d_out, int out_size, void* d_ws, size_t ws_size,
                              hipStream_t stream) {
    const float* roi_feat = (const float*)d_in[0];
    const float* ref_feat = (const float*)d_in[1];
    const float* rois1    = (const float*)d_in[2];
    const float* rois2    = (const float*)d_in[3];
    const float* Wq       = (const float*)d_in[4];
    const float* bq       = (const float*)d_in[5];
    const float* Wk       = (const float*)d_in[6];
    const float* bk       = (const float*)d_in[7];
    const float* Wg       = (const float*)d_in[8];
    const float* bg       = (const float*)d_in[9];
    const float* Wv       = (const float*)d_in[10];
    const float* bv       = (const float*)d_in[11];
    float* out = (float*)d_out;

    // ws (bytes): Qf 0-2M | Kf 2-4M | Vf 4-6M | AWt 6-38M
    char* ws = (char*)d_ws;
    __bf16* Qf  = (__bf16*)(ws + 0);
    __bf16* Kf  = (__bf16*)(ws + (2u << 20));
    __bf16* Vf  = (__bf16*)(ws + (4u << 20));
    __half* AWt = (__half*)(ws + (6u << 20));

    dim3 blk(256);
    fused_mid<<<dim3(4288), blk, 0, stream>>>(roi_feat, ref_feat, Wq, Wk, Wv,
                                              bq, bk, Qf, Kf, Vf,
                                              rois1, rois2, Wg, bg, AWt);
    attn_mfma<<<dim3(64, 16), blk, 0, stream>>>(Qf, Kf, Vf, AWt, bv, out);
}

// Round 14
// 143.065 us; speedup vs baseline: 1.4919x; 1.0403x over previous
//
#include <hip/hip_runtime.h>
#include <hip/hip_fp16.h>
#include <cstddef>

#define N_ 1024
#define M_ 1024
#define D_ 1024
#define G_ 16
#define DG_ 64

typedef __bf16 bf16x8 __attribute__((ext_vector_type(8)));
typedef _Float16 f16x8 __attribute__((ext_vector_type(8)));
typedef float f32x4 __attribute__((ext_vector_type(4)));

// Fragment-major layout helpers.
__device__ __forceinline__ size_t qkf_idx(int g, int rb, int ks, int lane) {
    return ((((size_t)(g * 64 + rb)) * 2 + ks) * 64 + lane) * 8;
}
__device__ __forceinline__ size_t vf_idx(int g, int ot, int mc, int lane) {
    return ((((size_t)(g * 4 + ot)) * 32 + mc) * 64 + lane) * 8;
}
// AWt layout v2 (R13): [mb(64)][n(1024)][g(16)][m16(16)] — posbias-coalesced.
__device__ __forceinline__ size_t awt_idx(int g, int mb, int n, int quad) {
    return (((size_t)(mb * 1024 + n)) * 16 + g) * 16 + quad * 4;
}

// ---------------------------------------------------------------------------
// Fused dispatch #1 (R13 verbatim): blocks 0..191 = gemm (128x128 tile, BK=64,
// fp32 weights transpose-cast during staging); blocks 192..4287 = posbias.
// ---------------------------------------------------------------------------
__global__ __launch_bounds__(256)
void fused_mid(const float* __restrict__ roi, const float* __restrict__ ref,
               const float* __restrict__ Wq, const float* __restrict__ Wk,
               const float* __restrict__ Wv,
               const float* __restrict__ bq, const float* __restrict__ bk,
               __bf16* __restrict__ Qf, __bf16* __restrict__ Kf,
               __bf16* __restrict__ Vf,
               const float* __restrict__ rois1, const float* __restrict__ rois2,
               const float* __restrict__ Wg, const float* __restrict__ bg,
               __half* __restrict__ AWt)
{
    __shared__ __align__(16) char smem[36864];
    const int b = blockIdx.x;
    const int tid = threadIdx.x;
    const int w = tid >> 6, lane = tid & 63;
    const int quad = lane >> 4, l15 = lane & 15;

    if (b < 192) {
        const int z = b >> 6, t6 = b & 63;
        const float* A = (z == 0) ? roi : ref;
        const float* Wf = (z == 0) ? Wq : (z == 1) ? Wk : Wv;
        const int i0 = (t6 >> 3) * 128, j0 = (t6 & 7) * 128;
        const int iw = (w & 1) * 64, jw = (w >> 1) * 64;

        __bf16(*As)[72] = (__bf16(*)[72])smem;
        __bf16(*Bs)[72] = (__bf16(*)[72])(smem + 18432);

        f32x4 acc[4][4] = {};

        for (int k0 = 0; k0 < D_; k0 += 64) {
            __syncthreads();
            #pragma unroll
            for (int it = 0; it < 8; ++it) {
                const int idx = tid + 256 * it;
                const int row = idx >> 4, c = idx & 15;
                float4 a = *(const float4*)&A[(size_t)(i0 + row) * D_ + k0 + c * 4];
                __bf16 p[4] = {(__bf16)a.x, (__bf16)a.y, (__bf16)a.z, (__bf16)a.w};
                *(uint2*)&As[row][c * 4] = *(const uint2*)p;
            }
            if (z < 2) {
                #pragma unroll
                for (int it = 0; it < 8; ++it) {
                    const int idx = tid + 256 * it;
                    const int jl = idx & 127;
                    const int kc = idx >> 7;
                    const float* src = &Wf[(size_t)(k0 + kc * 4) * D_ + j0 + jl];
                    __bf16 p[4];
                    p[0] = (__bf16)src[0];
                    p[1] = (__bf16)src[D_];
                    p[2] = (__bf16)src[2 * D_];
                    p[3] = (__bf16)src[3 * D_];
                    *(uint2*)&Bs[jl][kc * 4] = *(const uint2*)p;
                }
            } else {
                #pragma unroll
                for (int it = 0; it < 8; ++it) {
                    const int idx = tid + 256 * it;
                    const int row = idx >> 4, c = idx & 15;
                    float4 a = *(const float4*)&Wf[(size_t)(j0 + row) * D_ + k0 + c * 4];
                    __bf16 p[4] = {(__bf16)a.x, (__bf16)a.y, (__bf16)a.z, (__bf16)a.w};
                    *(uint2*)&Bs[row][c * 4] = *(const uint2*)p;
                }
            }
            __syncthreads();
            #pragma unroll
            for (int ks = 0; ks < 2; ++ks) {
                bf16x8 af[4], bfr[4];
                #pragma unroll
                for (int t = 0; t < 4; ++t) {
                    af[t]  = *(const bf16x8*)&As[iw + t * 16 + l15][ks * 32 + quad * 8];
                    bfr[t] = *(const bf16x8*)&Bs[jw + t * 16 + l15][ks * 32 + quad * 8];
                }
                #pragma unroll
                for (int ti = 0; ti < 4; ++ti)
                    #pragma unroll
                    for (int tj = 0; tj < 4; ++tj)
                        acc[ti][tj] = __builtin_amdgcn_mfma_f32_16x16x32_bf16(
                            af[ti], bfr[tj], acc[ti][tj], 0, 0, 0);
            }
        }

        if (z < 2) {
            const float* bias = (z == 0) ? bq : bk;
            __bf16* dst = (z == 0) ? Qf : Kf;
            const float scale = (z == 0) ? 0.125f : 1.0f;
            #pragma unroll
            for (int ti = 0; ti < 4; ++ti) {
                const int rb = (i0 + iw + ti * 16) >> 4;
                #pragma unroll
                for (int tj = 0; tj < 4; ++tj) {
                    const int go = j0 + jw + tj * 16 + l15;
                    const int g = go >> 6, ks = (go >> 5) & 1;
                    const int lanef = ((go >> 3) & 3) * 16;
                    const int jf = go & 7;
                    const float bb = bias[go];
                    __bf16* base = dst + qkf_idx(g, rb, ks, 0) + jf;
                    #pragma unroll
                    for (int r = 0; r < 4; ++r)
                        base[(size_t)(lanef + quad * 4 + r) * 8] =
                            (__bf16)((acc[ti][tj][r] + bb) * scale);
                }
            }
        } else {
            #pragma unroll
            for (int ti = 0; ti < 4; ++ti) {
                const int mbase = i0 + iw + ti * 16 + quad * 4;
                const int mc = mbase >> 5, quadv = (mbase >> 3) & 3, jb = mbase & 7;
                #pragma unroll
                for (int tj = 0; tj < 4; ++tj) {
                    const int go = j0 + jw + tj * 16 + l15;
                    const int g = go >> 6, ot = (go >> 4) & 3, o15 = go & 15;
                    __bf16 p[4];
                    #pragma unroll
                    for (int r = 0; r < 4; ++r) p[r] = (__bf16)acc[ti][tj][r];
                    *(uint2*)&Vf[vf_idx(g, ot, mc, quadv * 16 + o15) + jb] =
                        *(const uint2*)p;
                }
            }
        }
        return;
    }

    // ---------------- posbias branch (R13 verbatim) ----------------
    const int pb = b - 192;
    const int n = pb >> 2;
    const int m0w = (pb & 3) * 256 + w * 64;

    const float xmin = rois1[n * 4 + 0], ymin = rois1[n * 4 + 1];
    const float xmax = rois1[n * 4 + 2], ymax = rois1[n * 4 + 3];
    const float wn  = xmax - xmin + 1.f, hn  = ymax - ymin + 1.f;
    const float cxn = 0.5f * (xmin + xmax), cyn = 0.5f * (ymin + ymax);

    f16x8 wgf[2];
    #pragma unroll
    for (int ks = 0; ks < 2; ++ks) {
        const float* p = &Wg[l15 * 64 + ks * 32 + quad * 8];
        float4 a = *(const float4*)p;
        float4 bb = *(const float4*)(p + 4);
        wgf[ks][0] = (_Float16)a.x; wgf[ks][1] = (_Float16)a.y;
        wgf[ks][2] = (_Float16)a.z; wgf[ks][3] = (_Float16)a.w;
        wgf[ks][4] = (_Float16)bb.x; wgf[ks][5] = (_Float16)bb.y;
        wgf[ks][6] = (_Float16)bb.z; wgf[ks][7] = (_Float16)bb.w;
    }
    const float bgv = bg[l15];

    const float fr8[8] = {100.0f, 42.16965f, 17.782794f, 7.4989421f,
                          3.1622777f, 1.3335214f, 0.56234133f, 0.23713737f};
    const float phase = (quad & 1) ? 1.5707963267948966f : 0.f;

    #pragma unroll
    for (int ti = 0; ti < 4; ++ti) {
        const int mt0 = m0w + ti * 16;
        const int m = mt0 + l15;
        float4 r2 = *(const float4*)&rois2[m * 4];
        const float wr  = r2.z - r2.x + 1.f, hr  = r2.w - r2.y + 1.f;
        const float cxr = 0.5f * (r2.x + r2.z), cyr = 0.5f * (r2.y + r2.w);

        const float f0 = __logf(fabsf((cxn - cxr) / wn) + 0.001f);
        const float f1 = __logf(fabsf((cyn - cyr) / hn) + 0.001f);
        const float f2 = __logf(wn / wr);
        const float f3 = __logf(hn / hr);
        const float fa = (quad & 2) ? f1 : f0;
        const float fb = (quad & 2) ? f3 : f2;

        f32x4 acc = {};
        #pragma unroll
        for (int ks = 0; ks < 2; ++ks) {
            const float feat = ks ? fb : fa;
            f16x8 ef;
            #pragma unroll
            for (int j = 0; j < 8; ++j)
                ef[j] = (_Float16)__sinf(fmaf(feat, fr8[j], phase));
            acc = __builtin_amdgcn_mfma_f32_16x16x32_f16(ef, wgf[ks], acc, 0, 0, 0);
        }

        __half p[4];
        #pragma unroll
        for (int r = 0; r < 4; ++r)
            p[r] = __float2half(fmaxf(acc[r] + bgv, 0.f) + 1e-6f);
        *(uint2*)&AWt[awt_idx(l15, mt0 >> 4, n, quad)] = *(const uint2*)p;
    }
}

// ---------------------------------------------------------------------------
// Wave-autonomous MFMA attention. LDS union v2: Ps (loop-live, 9216B) shares
// the same LDS as accb/lsb (epilogue-live, 17664B) -> 17.7KB total, 7 blocks/CU
// (was 36.9KB / 4 blocks). Barrier between the two lifetimes makes it safe.
// ---------------------------------------------------------------------------
__global__ __launch_bounds__(256)
void attn_mfma(const __bf16* __restrict__ Qf, const __bf16* __restrict__ Kf,
               const __bf16* __restrict__ Vf, const __half* __restrict__ AWt,
               const float* __restrict__ bv, float* __restrict__ out)
{
    __shared__ __align__(16) char smem[17664];

    const int tid = threadIdx.x;
    const int w = tid >> 6, lane = tid & 63;
    const int quad = lane >> 4, l15 = lane & 15;
    const int nb = blockIdx.x, n0 = nb * 16, g = blockIdx.y;

    __bf16(*Psw)[72] = (__bf16(*)[72])(smem + w * 2304);       // [16][72], wave-private
    float(*accb)[64][17] = (float(*)[64][17])smem;             // [4][64][17]
    float(*lsb)[16] = (float(*)[16])(smem + 17408);            // [4][16]

    bf16x8 qf[2];
    qf[0] = *(const bf16x8*)&Qf[qkf_idx(g, nb, 0, lane)];
    qf[1] = *(const bf16x8*)&Qf[qkf_idx(g, nb, 1, lane)];

    f32x4 acc[4] = {};
    float llocal = 0.f;

    #pragma unroll
    for (int t64 = 0; t64 < 4; ++t64) {
        const int mt = w * 4 + t64;

        f32x4 s[4];
        #pragma unroll
        for (int t = 0; t < 4; ++t) {
            bf16x8 ka0 = *(const bf16x8*)&Kf[qkf_idx(g, mt * 4 + t, 0, lane)];
            bf16x8 ka1 = *(const bf16x8*)&Kf[qkf_idx(g, mt * 4 + t, 1, lane)];
            f32x4 z = {};
            z = __builtin_amdgcn_mfma_f32_16x16x32_bf16(ka0, qf[0], z, 0, 0, 0);
            s[t] = __builtin_amdgcn_mfma_f32_16x16x32_bf16(ka1, qf[1], z, 0, 0, 0);
        }

        #pragma unroll
        for (int t = 0; t < 4; ++t) {
            uint2 au = *(const uint2*)&AWt[awt_idx(g, mt * 4 + t, n0 + l15, quad)];
            const __half* a4 = (const __half*)&au;
            __bf16 pk[4];
            #pragma unroll
            for (int r = 0; r < 4; ++r) {
                const float p = __half2float(a4[r]) * __expf(s[t][r]);
                llocal += p;
                pk[r] = (__bf16)p;
            }
            *(uint2*)&Psw[l15][t * 16 + quad * 4] = *(const uint2*)pk;
        }

        #pragma unroll
        for (int mcl = 0; mcl < 2; ++mcl) {
            bf16x8 pbf = *(const bf16x8*)&Psw[l15][mcl * 32 + quad * 8];
            #pragma unroll
            for (int ot = 0; ot < 4; ++ot) {
                bf16x8 va = *(const bf16x8*)&Vf[vf_idx(g, ot, mt * 2 + mcl, lane)];
                acc[ot] = __builtin_amdgcn_mfma_f32_16x16x32_bf16(va, pbf, acc[ot], 0, 0, 0);
            }
        }
    }

    llocal += __shfl_xor(llocal, 16, 64);
    llocal += __shfl_xor(llocal, 32, 64);

    __syncthreads();   // Ps lifetime ends for ALL waves before accb reuses the LDS

    #pragma unroll
    for (int ot = 0; ot < 4; ++ot)
        #pragma unroll
        for (int r = 0; r < 4; ++r)
            accb[w][ot * 16 + quad * 4 + r][l15] = acc[ot][r];
    if (quad == 0) lsb[w][l15] = llocal;
    __syncthreads();

    const float lt = lsb[0][l15] + lsb[1][l15] + lsb[2][l15] + lsb[3][l15];
    const float inv = 1.f / lt;
    #pragma unroll
    for (int r = 0; r < 4; ++r) {
        const int o = w * 16 + quad * 4 + r;
        const int ogl = g * 64 + o;
        const float v = accb[0][o][l15] + accb[1][o][l15] +
                        accb[2][o][l15] + accb[3][o][l15];
        out[(size_t)(n0 + l15) * D_ + ogl] = v * inv + bv[ogl];
    }
}

extern "C" void kernel_launch(void* const* d_in, const int* in_sizes, int n_in,
                              void* d_out, int out_size, void* d_ws, size_t ws_size,
                              hipStream_t stream) {
    const float* roi_feat = (const float*)d_in[0];
    const float* ref_feat = (const float*)d_in[1];
    const float* rois1    = (const float*)d_in[2];
    const float* rois2    = (const float*)d_in[3];
    const float* Wq       = (const float*)d_in[4];
    const float* bq       = (const float*)d_in[5];
    const float* Wk       = (const float*)d_in[6];
    const float* bk       = (const float*)d_in[7];
    const float* Wg       = (const float*)d_in[8];
    const float* bg       = (const float*)d_in[9];
    const float* Wv       = (const float*)d_in[10];
    const float* bv       = (const float*)d_in[11];
    float* out = (float*)d_out;

    // ws (bytes): Qf 0-2M | Kf 2-4M | Vf 4-6M | AWt 6-38M
    char* ws = (char*)d_ws;
    __bf16* Qf  = (__bf16*)(ws + 0);
    __bf16* Kf  = (__bf16*)(ws + (2u << 20));
    __bf16* Vf  = (__bf16*)(ws + (4u << 20));
    __half* AWt = (__half*)(ws + (6u << 20));

    dim3 blk(256);
    fused_mid<<<dim3(4288), blk, 0, stream>>>(roi_feat, ref_feat, Wq, Wk, Wv,
                                              bq, bk, Qf, Kf, Vf,
                                              rois1, rois2, Wg, bg, AWt);
    attn_mfma<<<dim3(64, 16), blk, 0, stream>>>(Qf, Kf, Vf, AWt, bv, out);
}